// Round 8
// baseline (197.180 us; speedup 1.0000x reference)
//
#include <hip/hip_runtime.h>
#include <cstddef>
#include <cstdint>

// CausalSelfAttention, bf16-MFMA pipeline, round 7.
// Round 6 structure with the spill bug fixed: __launch_bounds__(512) (the
// ",4" min-waves arg capped VGPR at 64 and spilled ~200MB of scratch).
//   cvtx:      x fp32 -> bf16
//   wtrans:    W fp32 [K][N] -> W^T bf16 [N][K]  (x4 weights)
//   gemm_qkv:  fused q/k/v projection (Q pre-scaled by 0.125*log2e)
//   gemm_bt<2>: output projection
//   attn_big:  flash attention; swapped QK^T (softmax in-lane); PV 16x16x16
//              with P in registers; K/V double-buffered LDS staged via
//              global_load_lds with pre-swizzled global source (1 barrier
//              per iter); fast-path softmax; defer-max (T13); setprio (T5);
//              XCD swizzle (T1).

namespace {

typedef unsigned short u16;
typedef unsigned int u32;
typedef __attribute__((ext_vector_type(8))) short s8v;   // 8 bf16 (4 VGPR)
typedef __attribute__((ext_vector_type(4))) short s4v;   // 4 bf16 (2 VGPR)
typedef __attribute__((ext_vector_type(4))) float f4v;

constexpr int Bn = 4, Tn = 2048, Cn = 1024;
constexpr int Mn = Bn * Tn;      // 8192
constexpr int KVB = 128;         // k-tile rows
constexpr int NT128 = Tn / 128;  // 16 tiles
constexpr float QSCALE = 0.125f * 1.44269504f;  // 1/sqrt(64) * log2(e)

__device__ __forceinline__ u16 bfc(float f) {  // fp32 -> bf16 (RNE, native)
  return __builtin_bit_cast(u16, (__bf16)f);
}

__device__ __forceinline__ float ex2(float x) {
#if __has_builtin(__builtin_amdgcn_exp2f)
  return __builtin_amdgcn_exp2f(x);
#else
  return exp2f(x);
#endif
}

__device__ __forceinline__ f4v mfma16(s8v a, s8v b, f4v c) {
  return __builtin_amdgcn_mfma_f32_16x16x32_bf16(a, b, c, 0, 0, 0);
}

__device__ __forceinline__ f4v mfma16k16(s4v a, s4v b, f4v c) {
#if __has_builtin(__builtin_amdgcn_mfma_f32_16x16x16bf16_1k)
  return __builtin_amdgcn_mfma_f32_16x16x16bf16_1k(a, b, c, 0, 0, 0);
#else
  f4v d = c;
  asm("v_mfma_f32_16x16x16_bf16 %0, %1, %2, %0" : "+v"(d) : "v"(a), "v"(b));
  return d;
#endif
}

typedef __attribute__((address_space(1))) const u32 gas_u32;
typedef __attribute__((address_space(3))) u32 las_u32;
__device__ __forceinline__ void gl_lds16(const void* g, void* l) {
  __builtin_amdgcn_global_load_lds((gas_u32*)g, (las_u32*)l, 16, 0, 0);
}

// ---------------- x -> bf16 ----------------
__global__ __launch_bounds__(256) void cvtx(const float* __restrict__ in,
                                            u16* __restrict__ out) {
  const size_t i = ((size_t)blockIdx.x * 256 + threadIdx.x) * 8;
  const float4 a = *(const float4*)(in + i);
  const float4 b = *(const float4*)(in + i + 4);
  alignas(16) u16 t[8] = {bfc(a.x), bfc(a.y), bfc(a.z), bfc(a.w),
                          bfc(b.x), bfc(b.y), bfc(b.z), bfc(b.w)};
  *(s8v*)(out + i) = *(const s8v*)t;
}

// ---------------- W [K][N] fp32 -> W^T [N][K] bf16 ----------------
__global__ __launch_bounds__(256) void wtrans(
    const float* __restrict__ w0, const float* __restrict__ w1,
    const float* __restrict__ w2, const float* __restrict__ w3,
    u16* __restrict__ o0, u16* __restrict__ o1, u16* __restrict__ o2,
    u16* __restrict__ o3) {
  const float* W;
  u16* O;
  switch (blockIdx.z) {
    case 0: W = w0; O = o0; break;
    case 1: W = w1; O = o1; break;
    case 2: W = w2; O = o2; break;
    default: W = w3; O = o3; break;
  }
  __shared__ float Tsh[64][65];
  const int tid = threadIdx.x;
  const int n0 = blockIdx.x * 64, k0 = blockIdx.y * 64;
  {
    const int rk = tid >> 2, c0 = (tid & 3) * 16;
#pragma unroll
    for (int u = 0; u < 4; ++u) {
      const float4 v = *(const float4*)&W[(size_t)(k0 + rk) * Cn + n0 + c0 + u * 4];
      Tsh[rk][c0 + u * 4 + 0] = v.x;
      Tsh[rk][c0 + u * 4 + 1] = v.y;
      Tsh[rk][c0 + u * 4 + 2] = v.z;
      Tsh[rk][c0 + u * 4 + 3] = v.w;
    }
  }
  __syncthreads();
  {
    const int rn = tid >> 2, ck0 = (tid & 3) * 16;
    alignas(16) u16 t[16];
#pragma unroll
    for (int u = 0; u < 16; ++u) t[u] = bfc(Tsh[ck0 + u][rn]);
    *(s8v*)&O[(size_t)(n0 + rn) * Cn + k0 + ck0] = *(const s8v*)&t[0];
    *(s8v*)&O[(size_t)(n0 + rn) * Cn + k0 + ck0 + 8] = *(const s8v*)&t[8];
  }
}

// ---------------- GEMM body (m97 structure) ----------------
// OUT_MODE 0: bf16  1: V^T head-major  2: fp32  3: bf16 * QSCALE (for Q)
template <int OUT_MODE>
__device__ __forceinline__ void gemm_body(const u16* __restrict__ A,
                                          const u16* __restrict__ Bt,
                                          void* __restrict__ Cout, int bm,
                                          int bn, u16* As, u16* Bs) {
  const int N = Cn, K = Cn;
  const int tid = threadIdx.x;
  const int l = tid & 63, w = tid >> 6;
  const int lr = l & 15, lh = l >> 4;
  const int lrow = tid >> 2;
  const int lkcol = (tid & 3) * 8;
  const u16* Ag = A + (size_t)(bm * 128 + lrow) * K + lkcol;
  const u16* Bg = Bt + (size_t)(bn * 128 + lrow) * K + lkcol;
  const int wm = (w >> 1) * 64, wn = (w & 1) * 64;
  f4v acc[4][4] = {};
  for (int k0 = 0; k0 < K; k0 += 32) {
    __syncthreads();
    gl_lds16(Ag + k0, &As[(size_t)tid * 8]);
    gl_lds16(Ag + (size_t)64 * K + k0, &As[2048 + (size_t)tid * 8]);
    gl_lds16(Bg + k0, &Bs[(size_t)tid * 8]);
    gl_lds16(Bg + (size_t)64 * K + k0, &Bs[2048 + (size_t)tid * 8]);
    __syncthreads();
    s8v af[4], bfr[4];
#pragma unroll
    for (int i = 0; i < 4; ++i)
      af[i] = *(const s8v*)&As[(wm + i * 16 + lr) * 32 + lh * 8];
#pragma unroll
    for (int j = 0; j < 4; ++j)
      bfr[j] = *(const s8v*)&Bs[(wn + j * 16 + lr) * 32 + lh * 8];
    __builtin_amdgcn_s_setprio(1);
#pragma unroll
    for (int i = 0; i < 4; ++i)
#pragma unroll
      for (int j = 0; j < 4; ++j)
        acc[i][j] = mfma16(af[i], bfr[j], acc[i][j]);
    __builtin_amdgcn_s_setprio(0);
  }
  // D layout: col = lane&15, row = (lane>>4)*4 + reg  [m89]
  if (OUT_MODE == 2) {
    float* Cf = (float*)Cout;
#pragma unroll
    for (int i = 0; i < 4; ++i) {
      const int row = bm * 128 + wm + i * 16 + lh * 4;
#pragma unroll
      for (int j = 0; j < 4; ++j) {
        const int col = bn * 128 + wn + j * 16 + lr;
#pragma unroll
        for (int r = 0; r < 4; ++r)
          Cf[(size_t)(row + r) * N + col] = acc[i][j][r];
      }
    }
  } else if (OUT_MODE == 0 || OUT_MODE == 3) {
    u16* Cb = (u16*)Cout;
    const float sc = (OUT_MODE == 3) ? QSCALE : 1.0f;
#pragma unroll
    for (int i = 0; i < 4; ++i) {
      const int row = bm * 128 + wm + i * 16 + lh * 4;
#pragma unroll
      for (int j = 0; j < 4; ++j) {
        const int col = bn * 128 + wn + j * 16 + lr;
#pragma unroll
        for (int r = 0; r < 4; ++r)
          Cb[(size_t)(row + r) * N + col] = bfc(acc[i][j][r] * sc);
      }
    }
  } else {
    // V^T head-major: Vt[((b*16+h)*64+d)][t]
    u16* Vt = (u16*)Cout;
#pragma unroll
    for (int i = 0; i < 4; ++i) {
      const int row0 = bm * 128 + wm + i * 16 + lh * 4;
      const int bq = row0 >> 11, t0 = row0 & 2047;
#pragma unroll
      for (int j = 0; j < 4; ++j) {
        const int col = bn * 128 + wn + j * 16 + lr;
        const int hh = col >> 6, dd = col & 63;
        alignas(8) u16 t4[4];
#pragma unroll
        for (int r = 0; r < 4; ++r) t4[r] = bfc(acc[i][j][r]);
        *(s4v*)&Vt[((size_t)((bq * 16 + hh) * 64 + dd)) * Tn + t0] =
            *(const s4v*)t4;
      }
    }
  }
}

// Fused q/k/v projection: grid 1536 = 3 x (64 bm x 8 bn), XCD-swizzled.
__global__ __launch_bounds__(256) void gemm_qkv(
    const u16* __restrict__ A, const u16* __restrict__ btq,
    const u16* __restrict__ btk, const u16* __restrict__ btv,
    u16* __restrict__ qb, u16* __restrict__ kb, u16* __restrict__ vt) {
  __shared__ __align__(16) u16 As[4096], Bs[4096];
  const int bid = blockIdx.x;                   // 0..1535
  const int wg = (bid & 7) * 192 + (bid >> 3);  // bijective (1536 % 8 == 0)
  const int which = wg >> 9, inner = wg & 511;
  const int bm = inner & 63, bn = inner >> 6;
  if (which == 0)
    gemm_body<3>(A, btq, qb, bm, bn, As, Bs);   // Q pre-scaled
  else if (which == 1)
    gemm_body<0>(A, btk, kb, bm, bn, As, Bs);
  else
    gemm_body<1>(A, btv, vt, bm, bn, As, Bs);
}

template <int OUT_MODE>
__global__ __launch_bounds__(256) void gemm_bt(const u16* __restrict__ A,
                                               const u16* __restrict__ Bt,
                                               void* __restrict__ Cout) {
  __shared__ __align__(16) u16 As[4096], Bs[4096];
  const int bid = blockIdx.x;                 // 0..511
  const int wg = (bid & 7) * 64 + (bid >> 3);
  const int bm = wg & 63, bn = wg >> 6;
  gemm_body<OUT_MODE>(A, Bt, Cout, bm, bn, As, Bs);
}

// ---------------- Flash attention, swapped-QK^T ----------------
// K/V staging via global_load_lds: LDS linear (row, chunk) holds global
// chunk (chunk ^ (row&7)) -> readers use the same XOR (rule #21 satisfied:
// inverse-swizzled source + swizzled read, linear dest).
__device__ __forceinline__ void stage_kv(const u16* __restrict__ kgb,
                                         const u16* __restrict__ vtb,
                                         u16* __restrict__ Kb,
                                         u16* __restrict__ Vb, int k0,
                                         int tid) {
  // K tile: 128 rows x 64 d = 1024 16B-slots; slot = row*8 + ch
#pragma unroll
  for (int is = 0; is < 2; ++is) {
    const int slot = is * 512 + tid;
    const int row = slot >> 3, ch = slot & 7;
    gl_lds16(kgb + (size_t)(k0 + row) * Cn + ((ch ^ (row & 7)) * 8),
             &Kb[slot * 8]);
  }
  // V^T tile: 64 rows(d) x 128 t = 1024 slots; slot = d*16 + ch
#pragma unroll
  for (int is = 0; is < 2; ++is) {
    const int slot = is * 512 + tid;
    const int d = slot >> 4, ch = slot & 15;
    gl_lds16(vtb + (size_t)d * Tn + k0 + ((ch ^ (d & 7)) * 8), &Vb[slot * 8]);
  }
}

// One tile-step: S^T = mfma(K,Q); in-lane softmax (fast path: no cross-lane
// ops); PV via 16x16x16 MFMA with P as the A-fragment straight from regs.
__device__ __forceinline__ void attn_step(const s8v* aq,
                                          const u16* __restrict__ Ks,
                                          const u16* __restrict__ Vs, int ln,
                                          int w, int lr, int lh, bool diag,
                                          int k0, int q0, float& m_i,
                                          float& l_i, f4v* o) {
  f4v s[8] = {};
  {
    const int sw = lr & 7;
    __builtin_amdgcn_s_setprio(1);
#pragma unroll
    for (int n = 0; n < 8; ++n) {
      const int rk = n * 16 + lr;
#pragma unroll
      for (int kd = 0; kd < 2; ++kd) {
        const s8v bk = *(const s8v*)&Ks[rk * 64 + (((kd * 4 + lh) ^ sw) * 8)];
        s[n] = mfma16(bk, aq[kd], s[n]);  // SWAPPED: S^T[k][q]
      }
    }
    __builtin_amdgcn_s_setprio(0);
  }
  const int qg = q0 + w * 16 + lr;
  float rm = -1e30f;
  if (diag) {
#pragma unroll
    for (int n = 0; n < 8; ++n)
#pragma unroll
      for (int r = 0; r < 4; ++r) {
        float x = s[n][r];
        if (k0 + n * 16 + lh * 4 + r > qg) x = -1e30f;
        s[n][r] = x;
        rm = fmaxf(rm, x);
      }
  } else {
#pragma unroll
    for (int n = 0; n < 8; ++n)
      rm = fmaxf(rm, fmaxf(fmaxf(s[n][0], s[n][1]), fmaxf(s[n][2], s[n][3])));
  }
  // T13 defer-max: local-max check; cross-lane reduce only on slow path.
  if (!__all(rm <= m_i + 11.5f)) {
    float rr = fmaxf(rm, __shfl_xor(rm, 16));
    rr = fmaxf(rr, __shfl_xor(rr, 32));
    const float mnew = fmaxf(m_i, rr);
    const float al = ex2(m_i - mnew);
    m_i = mnew;
    l_i *= al;
#pragma unroll
    for (int r = 0; r < 4; ++r) {
      const float ar = __shfl(al, (ln & 48) | (lh * 4 + r));
#pragma unroll
      for (int n2 = 0; n2 < 4; ++n2) o[n2][r] *= ar;
    }
  }
  float rs = 0.f;
#pragma unroll
  for (int n = 0; n < 8; ++n) {
    const float p0 = ex2(s[n][0] - m_i);
    const float p1 = ex2(s[n][1] - m_i);
    const float p2 = ex2(s[n][2] - m_i);
    const float p3 = ex2(s[n][3] - m_i);
    rs += (p0 + p1) + (p2 + p3);
    const s4v pa = {(short)bfc(p0), (short)bfc(p1), (short)bfc(p2),
                    (short)bfc(p3)};
    __builtin_amdgcn_s_setprio(1);
#pragma unroll
    for (int n2 = 0; n2 < 4; ++n2) {
      const int d = n2 * 16 + lr;
      const int cl = (2 * n + (lh >> 1)) ^ (lr & 7);
      const s4v bv = *(const s4v*)&Vs[d * 128 + cl * 8 + (lh & 1) * 4];
      o[n2] = mfma16k16(pa, bv, o[n2]);  // O[q=lh*4+reg][d=n2*16+lr]
    }
    __builtin_amdgcn_s_setprio(0);
  }
  l_i += rs;  // per-lane partial; row-reduce deferred to epilogue
}

// Block: paired 128-row q-tiles (xp, 15-xp) -> uniform 17 steps.
// Grid 512 (8 pairs x 64 bh), 512 threads = 8 waves, XCD-swizzled.
// K/V double-buffered: one barrier per kt-iter.
__global__ __launch_bounds__(512) void attn_big(const u16* __restrict__ qg,
                                                const u16* __restrict__ kg,
                                                const u16* __restrict__ vtg,
                                                u16* __restrict__ yg) {
  __shared__ __align__(16) u16 Ks0[KVB * 64], Ks1[KVB * 64];  // 16 KB each
  __shared__ __align__(16) u16 Vs0[64 * KVB], Vs1[64 * KVB];  // 16 KB each
  const int tid = threadIdx.x;
  const int ln = tid & 63, w = tid >> 6;  // wave 0..7
  const int lr = ln & 15, lh = ln >> 4;
  const int bid = blockIdx.x;                  // 0..511
  const int wg = (bid & 7) * 64 + (bid >> 3);  // XCD chunking (512 % 8 == 0)
  const int bh = wg >> 3, xp = wg & 7;
  const int b = bh >> 4, h = bh & 15;
  const int tL = xp, tH = NT128 - 1 - xp;
  const int q0L = tL * 128, q0H = tH * 128;
  const u16* kgb = kg + (size_t)(b * Tn) * Cn + h * 64;
  const u16* vtb = vtg + (size_t)(bh * 64) * Tn;
  // Q-hoist: per-wave B-fragments in registers (Q already * QSCALE)
  s8v aqL[2], aqH[2];
  {
    const int row = w * 16 + lr;
#pragma unroll
    for (int kd = 0; kd < 2; ++kd) {
      aqL[kd] = *(const s8v*)&qg[(size_t)(b * Tn + q0L + row) * Cn + h * 64 +
                                 kd * 32 + lh * 8];
      aqH[kd] = *(const s8v*)&qg[(size_t)(b * Tn + q0H + row) * Cn + h * 64 +
                                 kd * 32 + lh * 8];
    }
  }
  float mL = -1e30f, lL = 0.f, mH = -1e30f, lH = 0.f;
  f4v oL[4] = {}, oH[4] = {};
  stage_kv(kgb, vtb, Ks0, Vs0, 0, tid);
  __syncthreads();  // buf0 ready (barrier drains vmcnt)
  for (int kt = 0; kt <= tH; ++kt) {
    const bool cur = kt & 1;
    const u16* Kb = cur ? Ks1 : Ks0;
    const u16* Vb = cur ? Vs1 : Vs0;
    if (kt < tH)  // async-stage next tile into the other buffer
      stage_kv(kgb, vtb, cur ? Ks0 : Ks1, cur ? Vs0 : Vs1, (kt + 1) * KVB,
               tid);
    attn_step(aqH, Kb, Vb, ln, w, lr, lh, kt == tH, kt * KVB, q0H, mH, lH,
              oH);
    if (kt <= tL)
      attn_step(aqL, Kb, Vb, ln, w, lr, lh, kt == tL, kt * KVB, q0L, mL, lL,
                oL);
    __syncthreads();  // next buffer ready; this buffer's readers done
  }
  {
    float ls = lH;
    ls += __shfl_xor(ls, 16);
    ls += __shfl_xor(ls, 32);
    const float linv = 1.0f / ls;
#pragma unroll
    for (int r = 0; r < 4; ++r) {
      const float iv = __shfl(linv, (ln & 48) | (lh * 4 + r));
      const int row = q0H + w * 16 + lh * 4 + r;
#pragma unroll
      for (int n2 = 0; n2 < 4; ++n2)
        yg[(size_t)(b * Tn + row) * Cn + h * 64 + n2 * 16 + lr] =
            bfc(oH[n2][r] * iv);
    }
  }
  {
    float ls = lL;
    ls += __shfl_xor(ls, 16);
    ls += __shfl_xor(ls, 32);
    const float linv = 1.0f / ls;
#pragma unroll
    for (int r = 0; r < 4; ++r) {
      const float iv = __shfl(linv, (ln & 48) | (lh * 4 + r));
      const int row = q0L + w * 16 + lh * 4 + r;
#pragma unroll
      for (int n2 = 0; n2 < 4; ++n2)
        yg[(size_t)(b * Tn + row) * Cn + h * 64 + n2 * 16 + lr] =
            bfc(oL[n2][r] * iv);
    }
  }
}

}  // namespace

extern "C" void kernel_launch(void* const* d_in, const int* in_sizes, int n_in,
                              void* d_out, int out_size, void* d_ws,
                              size_t ws_size, hipStream_t stream) {
  (void)in_sizes; (void)n_in; (void)out_size; (void)ws_size;
  const float* x = (const float*)d_in[0];
  const float* Wk = (const float*)d_in[1];
  const float* Wq = (const float*)d_in[2];
  const float* Wv = (const float*)d_in[3];
  const float* Wp = (const float*)d_in[4];
  float* out = (float*)d_out;
  char* ws = (char*)d_ws;

  u16* xb = (u16*)(ws);              // 16.8 MB
  u16* wqt = (u16*)(ws + 16777216);  // 2 MB each
  u16* wkt = (u16*)(ws + 18874368);
  u16* wvt = (u16*)(ws + 20971520);
  u16* wpt = (u16*)(ws + 23068672);
  u16* qb = (u16*)(ws + 25165824);  // 16.8 MB each
  u16* kb = (u16*)(ws + 41943040);
  u16* vt = (u16*)(ws + 58720256);  // head-major V^T [b][h][d][t]
  u16* yb = (u16*)(ws + 75497472);

  cvtx<<<dim3(4096), dim3(256), 0, stream>>>(x, xb);
  wtrans<<<dim3(16, 16, 4), dim3(256), 0, stream>>>(Wq, Wk, Wv, Wp, wqt, wkt,
                                                    wvt, wpt);
  gemm_qkv<<<dim3(1536), dim3(256), 0, stream>>>(xb, wqt, wkt, wvt, qb, kb,
                                                 vt);
  attn_big<<<dim3(512), dim3(512), 0, stream>>>(qb, kb, vt, yb);
  gemm_bt<2><<<dim3(512), dim3(256), 0, stream>>>(yb, wpt, out);
}

// Round 9
// 186.554 us; speedup vs baseline: 1.0570x; 1.0570x over previous
//
#include <hip/hip_runtime.h>
#include <cstddef>
#include <cstdint>

// CausalSelfAttention, bf16-MFMA pipeline, round 9.
// B=4, T=2048, C=1024, NH=16, HS=64.
//   cvtx:      x fp32 -> bf16
//   wtrans:    W fp32 [K][N] -> W^T bf16 [N][K]  (x4 weights)
//   gemm_qkv:  fused q/k/v projection (Q pre-scaled by 0.125*log2e;
//              V^T epilogue writes pi-permuted 128-tiles for b128 PV reads)
//   gemm_bt<2>: output projection
//   attn_big:  flash attention; swapped QK^T (softmax in-lane); PV 16x16x16
//              with P in registers; ALL LDS offsets hoisted out of kt-loop;
//              PV reads b128 (paired n via pi-permuted V layout);
//              defer-max (T13); setprio (T5); XCD swizzle (T1).

namespace {

typedef unsigned short u16;
typedef unsigned int u32;
typedef __attribute__((ext_vector_type(8))) short s8v;   // 8 bf16 (4 VGPR)
typedef __attribute__((ext_vector_type(4))) short s4v;   // 4 bf16 (2 VGPR)
typedef __attribute__((ext_vector_type(4))) float f4v;

constexpr int Bn = 4, Tn = 2048, Cn = 1024;
constexpr int Mn = Bn * Tn;      // 8192
constexpr int KVB = 128;         // k-tile rows
constexpr int NT128 = Tn / 128;  // 16 tiles
constexpr float QSCALE = 0.125f * 1.44269504f;  // 1/sqrt(64) * log2(e)

__device__ __forceinline__ u16 bfc(float f) {  // fp32 -> bf16 (RNE, native)
  return __builtin_bit_cast(u16, (__bf16)f);
}

__device__ __forceinline__ float ex2(float x) {
#if __has_builtin(__builtin_amdgcn_exp2f)
  return __builtin_amdgcn_exp2f(x);
#else
  return exp2f(x);
#endif
}

__device__ __forceinline__ f4v mfma16(s8v a, s8v b, f4v c) {
  return __builtin_amdgcn_mfma_f32_16x16x32_bf16(a, b, c, 0, 0, 0);
}

__device__ __forceinline__ f4v mfma16k16(s4v a, s4v b, f4v c) {
#if __has_builtin(__builtin_amdgcn_mfma_f32_16x16x16bf16_1k)
  return __builtin_amdgcn_mfma_f32_16x16x16bf16_1k(a, b, c, 0, 0, 0);
#else
  f4v d = c;
  asm("v_mfma_f32_16x16x16_bf16 %0, %1, %2, %0" : "+v"(d) : "v"(a), "v"(b));
  return d;
#endif
}

typedef __attribute__((address_space(1))) const u32 gas_u32;
typedef __attribute__((address_space(3))) u32 las_u32;
__device__ __forceinline__ void gl_lds16(const void* g, void* l) {
  __builtin_amdgcn_global_load_lds((gas_u32*)g, (las_u32*)l, 16, 0, 0);
}

// ---------------- x -> bf16 ----------------
__global__ __launch_bounds__(256) void cvtx(const float* __restrict__ in,
                                            u16* __restrict__ out) {
  const size_t i = ((size_t)blockIdx.x * 256 + threadIdx.x) * 8;
  const float4 a = *(const float4*)(in + i);
  const float4 b = *(const float4*)(in + i + 4);
  alignas(16) u16 t[8] = {bfc(a.x), bfc(a.y), bfc(a.z), bfc(a.w),
                          bfc(b.x), bfc(b.y), bfc(b.z), bfc(b.w)};
  *(s8v*)(out + i) = *(const s8v*)t;
}

// ---------------- W [K][N] fp32 -> W^T [N][K] bf16 ----------------
__global__ __launch_bounds__(256) void wtrans(
    const float* __restrict__ w0, const float* __restrict__ w1,
    const float* __restrict__ w2, const float* __restrict__ w3,
    u16* __restrict__ o0, u16* __restrict__ o1, u16* __restrict__ o2,
    u16* __restrict__ o3) {
  const float* W;
  u16* O;
  switch (blockIdx.z) {
    case 0: W = w0; O = o0; break;
    case 1: W = w1; O = o1; break;
    case 2: W = w2; O = o2; break;
    default: W = w3; O = o3; break;
  }
  __shared__ float Tsh[64][65];
  const int tid = threadIdx.x;
  const int n0 = blockIdx.x * 64, k0 = blockIdx.y * 64;
  {
    const int rk = tid >> 2, c0 = (tid & 3) * 16;
#pragma unroll
    for (int u = 0; u < 4; ++u) {
      const float4 v = *(const float4*)&W[(size_t)(k0 + rk) * Cn + n0 + c0 + u * 4];
      Tsh[rk][c0 + u * 4 + 0] = v.x;
      Tsh[rk][c0 + u * 4 + 1] = v.y;
      Tsh[rk][c0 + u * 4 + 2] = v.z;
      Tsh[rk][c0 + u * 4 + 3] = v.w;
    }
  }
  __syncthreads();
  {
    const int rn = tid >> 2, ck0 = (tid & 3) * 16;
    alignas(16) u16 t[16];
#pragma unroll
    for (int u = 0; u < 16; ++u) t[u] = bfc(Tsh[ck0 + u][rn]);
    *(s8v*)&O[(size_t)(n0 + rn) * Cn + k0 + ck0] = *(const s8v*)&t[0];
    *(s8v*)&O[(size_t)(n0 + rn) * Cn + k0 + ck0 + 8] = *(const s8v*)&t[8];
  }
}

// ---------------- GEMM body (m97 structure) ----------------
// OUT_MODE 0: bf16  1: V^T head-major pi-permuted  2: fp32  3: bf16 * QSCALE
template <int OUT_MODE>
__device__ __forceinline__ void gemm_body(const u16* __restrict__ A,
                                          const u16* __restrict__ Bt,
                                          void* __restrict__ Cout, int bm,
                                          int bn, u16* As, u16* Bs) {
  const int N = Cn, K = Cn;
  const int tid = threadIdx.x;
  const int l = tid & 63, w = tid >> 6;
  const int lr = l & 15, lh = l >> 4;
  const int lrow = tid >> 2;
  const int lkcol = (tid & 3) * 8;
  const u16* Ag = A + (size_t)(bm * 128 + lrow) * K + lkcol;
  const u16* Bg = Bt + (size_t)(bn * 128 + lrow) * K + lkcol;
  const int wm = (w >> 1) * 64, wn = (w & 1) * 64;
  f4v acc[4][4] = {};
  for (int k0 = 0; k0 < K; k0 += 32) {
    __syncthreads();
    gl_lds16(Ag + k0, &As[(size_t)tid * 8]);
    gl_lds16(Ag + (size_t)64 * K + k0, &As[2048 + (size_t)tid * 8]);
    gl_lds16(Bg + k0, &Bs[(size_t)tid * 8]);
    gl_lds16(Bg + (size_t)64 * K + k0, &Bs[2048 + (size_t)tid * 8]);
    __syncthreads();
    s8v af[4], bfr[4];
#pragma unroll
    for (int i = 0; i < 4; ++i)
      af[i] = *(const s8v*)&As[(wm + i * 16 + lr) * 32 + lh * 8];
#pragma unroll
    for (int j = 0; j < 4; ++j)
      bfr[j] = *(const s8v*)&Bs[(wn + j * 16 + lr) * 32 + lh * 8];
    __builtin_amdgcn_s_setprio(1);
#pragma unroll
    for (int i = 0; i < 4; ++i)
#pragma unroll
      for (int j = 0; j < 4; ++j)
        acc[i][j] = mfma16(af[i], bfr[j], acc[i][j]);
    __builtin_amdgcn_s_setprio(0);
  }
  // D layout: col = lane&15, row = (lane>>4)*4 + reg  [m89]
  if (OUT_MODE == 2) {
    float* Cf = (float*)Cout;
#pragma unroll
    for (int i = 0; i < 4; ++i) {
      const int row = bm * 128 + wm + i * 16 + lh * 4;
#pragma unroll
      for (int j = 0; j < 4; ++j) {
        const int col = bn * 128 + wn + j * 16 + lr;
#pragma unroll
        for (int r = 0; r < 4; ++r)
          Cf[(size_t)(row + r) * N + col] = acc[i][j][r];
      }
    }
  } else if (OUT_MODE == 0 || OUT_MODE == 3) {
    u16* Cb = (u16*)Cout;
    const float sc = (OUT_MODE == 3) ? QSCALE : 1.0f;
#pragma unroll
    for (int i = 0; i < 4; ++i) {
      const int row = bm * 128 + wm + i * 16 + lh * 4;
#pragma unroll
      for (int j = 0; j < 4; ++j) {
        const int col = bn * 128 + wn + j * 16 + lr;
#pragma unroll
        for (int r = 0; r < 4; ++r)
          Cb[(size_t)(row + r) * N + col] = bfc(acc[i][j][r] * sc);
      }
    }
  } else {
    // V^T head-major pi-permuted: within each 128-t tile, original
    // t = 32p+16s+4lh+j stored at p*32+lh*8+s*4+j (4-groups stay contiguous)
    u16* Vt = (u16*)Cout;
#pragma unroll
    for (int i = 0; i < 4; ++i) {
      const int row0 = bm * 128 + wm + i * 16 + lh * 4;
      const int bq = row0 >> 11;
      const int t0g = row0 & 2047;
      const int tau = t0g & 127;
      const int taup = ((tau >> 5) << 5) | (((tau >> 2) & 3) << 3) |
                       (((tau >> 4) & 1) << 2);
      const int t0p = (t0g & ~127) | taup;
#pragma unroll
      for (int j = 0; j < 4; ++j) {
        const int col = bn * 128 + wn + j * 16 + lr;
        const int hh = col >> 6, dd = col & 63;
        alignas(8) u16 t4[4];
#pragma unroll
        for (int r = 0; r < 4; ++r) t4[r] = bfc(acc[i][j][r]);
        *(s4v*)&Vt[((size_t)((bq * 16 + hh) * 64 + dd)) * Tn + t0p] =
            *(const s4v*)t4;
      }
    }
  }
}

// Fused q/k/v projection: grid 1536 = 3 x (64 bm x 8 bn), XCD-swizzled.
__global__ __launch_bounds__(256) void gemm_qkv(
    const u16* __restrict__ A, const u16* __restrict__ btq,
    const u16* __restrict__ btk, const u16* __restrict__ btv,
    u16* __restrict__ qb, u16* __restrict__ kb, u16* __restrict__ vt) {
  __shared__ __align__(16) u16 As[4096], Bs[4096];
  const int bid = blockIdx.x;                   // 0..1535
  const int wg = (bid & 7) * 192 + (bid >> 3);  // bijective (1536 % 8 == 0)
  const int which = wg >> 9, inner = wg & 511;
  const int bm = inner & 63, bn = inner >> 6;
  if (which == 0)
    gemm_body<3>(A, btq, qb, bm, bn, As, Bs);   // Q pre-scaled
  else if (which == 1)
    gemm_body<0>(A, btk, kb, bm, bn, As, Bs);
  else
    gemm_body<1>(A, btv, vt, bm, bn, As, Bs);
}

template <int OUT_MODE>
__global__ __launch_bounds__(256) void gemm_bt(const u16* __restrict__ A,
                                               const u16* __restrict__ Bt,
                                               void* __restrict__ Cout) {
  __shared__ __align__(16) u16 As[4096], Bs[4096];
  const int bid = blockIdx.x;                 // 0..511
  const int wg = (bid & 7) * 64 + (bid >> 3);
  const int bm = wg & 63, bn = wg >> 6;
  gemm_body<OUT_MODE>(A, Bt, Cout, bm, bn, As, Bs);
}

// ---------------- Flash attention, swapped-QK^T ----------------
// K/V staging via global_load_lds: LDS linear (row, chunk) holds global
// chunk (chunk ^ (row&7)) -> readers use the same XOR.
__device__ __forceinline__ void stage_kv(const u16* __restrict__ kgb,
                                         const u16* __restrict__ vtb,
                                         u16* __restrict__ Kb,
                                         u16* __restrict__ Vb, int k0,
                                         int tid) {
  // K tile: 128 rows x 64 d = 1024 16B-slots; slot = row*8 + ch
#pragma unroll
  for (int is = 0; is < 2; ++is) {
    const int slot = is * 512 + tid;
    const int row = slot >> 3, ch = slot & 7;
    gl_lds16(kgb + (size_t)(k0 + row) * Cn + ((ch ^ (row & 7)) * 8),
             &Kb[slot * 8]);
  }
  // V^T tile: 64 rows(d) x 128 t (pi-permuted global); slot = d*16 + ch
#pragma unroll
  for (int is = 0; is < 2; ++is) {
    const int slot = is * 512 + tid;
    const int d = slot >> 4, ch = slot & 15;
    gl_lds16(vtb + (size_t)d * Tn + k0 + ((ch ^ (d & 7)) * 8), &Vb[slot * 8]);
  }
}

// One tile-step. All LDS offsets (kb0,kb1,vch[4]) are hoisted lane constants;
// in-loop addresses are base + compile-time immediates.
__device__ __forceinline__ void attn_step(const s8v (&aq)[2],
                                          const u16* __restrict__ Ks,
                                          const u16* __restrict__ Vs, int kb0,
                                          int kb1, const int (&vch)[4], int ln,
                                          int lh, bool diag, int k0, int qg,
                                          float& m_i, float& l_i, f4v* o) {
  f4v s[8] = {};
  __builtin_amdgcn_s_setprio(1);
#pragma unroll
  for (int n = 0; n < 8; ++n) {
    const s8v bk0 = *(const s8v*)&Ks[kb0 + n * 1024];
    const s8v bk1 = *(const s8v*)&Ks[kb1 + n * 1024];
    s[n] = mfma16(bk0, aq[0], s[n]);  // SWAPPED: S^T[k][q]
    s[n] = mfma16(bk1, aq[1], s[n]);
  }
  __builtin_amdgcn_s_setprio(0);
  float rm = -1e30f;
  if (diag) {
#pragma unroll
    for (int n = 0; n < 8; ++n)
#pragma unroll
      for (int r = 0; r < 4; ++r) {
        float x = s[n][r];
        if (k0 + n * 16 + lh * 4 + r > qg) x = -1e30f;
        s[n][r] = x;
        rm = fmaxf(rm, x);
      }
  } else {
#pragma unroll
    for (int n = 0; n < 8; ++n)
      rm = fmaxf(rm, fmaxf(fmaxf(s[n][0], s[n][1]), fmaxf(s[n][2], s[n][3])));
  }
  // T13 defer-max: local-max check; cross-lane reduce only on slow path.
  if (!__all(rm <= m_i + 11.5f)) {
    float rr = fmaxf(rm, __shfl_xor(rm, 16));
    rr = fmaxf(rr, __shfl_xor(rr, 32));
    const float mnew = fmaxf(m_i, rr);
    const float al = ex2(m_i - mnew);
    m_i = mnew;
    l_i *= al;
#pragma unroll
    for (int r = 0; r < 4; ++r) {
      const float ar = __shfl(al, (ln & 48) | (lh * 4 + r));
#pragma unroll
      for (int n2 = 0; n2 < 4; ++n2) o[n2][r] *= ar;
    }
  }
  // exp + pack all 32 P values into 8 A-fragments (registers)
  s4v pa[8];
  float rs = 0.f;
#pragma unroll
  for (int n = 0; n < 8; ++n) {
    const float p0 = ex2(s[n][0] - m_i);
    const float p1 = ex2(s[n][1] - m_i);
    const float p2 = ex2(s[n][2] - m_i);
    const float p3 = ex2(s[n][3] - m_i);
    rs += (p0 + p1) + (p2 + p3);
    pa[n] = (s4v){(short)bfc(p0), (short)bfc(p1), (short)bfc(p2),
                  (short)bfc(p3)};
  }
  l_i += rs;  // per-lane partial; row-reduce deferred to epilogue
  // PV: b128 reads, each feeds two K=16 MFMAs (n=2p lo, n=2p+1 hi)
  __builtin_amdgcn_s_setprio(1);
#pragma unroll
  for (int n2 = 0; n2 < 4; ++n2) {
#pragma unroll
    for (int p = 0; p < 4; ++p) {
      const s8v vv = *(const s8v*)&Vs[vch[p] + n2 * 2048];
      const s4v lo = {vv[0], vv[1], vv[2], vv[3]};
      const s4v hi = {vv[4], vv[5], vv[6], vv[7]};
      o[n2] = mfma16k16(pa[2 * p], lo, o[n2]);
      o[n2] = mfma16k16(pa[2 * p + 1], hi, o[n2]);
    }
  }
  __builtin_amdgcn_s_setprio(0);
}

// Block: paired 128-row q-tiles (xp, 15-xp) -> uniform 17 steps.
// Grid 512 (8 pairs x 64 bh), 512 threads = 8 waves, XCD-swizzled.
// K/V double-buffered: one barrier per kt-iter.
__global__ __launch_bounds__(512) void attn_big(const u16* __restrict__ qg,
                                                const u16* __restrict__ kg,
                                                const u16* __restrict__ vtg,
                                                u16* __restrict__ yg) {
  __shared__ __align__(16) u16 Ks0[KVB * 64], Ks1[KVB * 64];  // 16 KB each
  __shared__ __align__(16) u16 Vs0[64 * KVB], Vs1[64 * KVB];  // 16 KB each
  const int tid = threadIdx.x;
  const int ln = tid & 63, w = tid >> 6;  // wave 0..7
  const int lr = ln & 15, lh = ln >> 4;
  const int bid = blockIdx.x;                  // 0..511
  const int wg = (bid & 7) * 64 + (bid >> 3);  // XCD chunking (512 % 8 == 0)
  const int bh = wg >> 3, xp = wg & 7;
  const int b = bh >> 4, h = bh & 15;
  const int tL = xp, tH = NT128 - 1 - xp;
  const int q0L = tL * 128, q0H = tH * 128;
  const u16* kgb = kg + (size_t)(b * Tn) * Cn + h * 64;
  const u16* vtb = vtg + (size_t)(bh * 64) * Tn;
  // hoisted lane-constant LDS offsets (elements)
  const int kb0 = lr * 64 + ((lh) ^ (lr & 7)) * 8;
  const int kb1 = lr * 64 + ((4 + lh) ^ (lr & 7)) * 8;
  int vch[4];
#pragma unroll
  for (int p = 0; p < 4; ++p)
    vch[p] = lr * 128 + ((p * 4 + lh) ^ (lr & 7)) * 8;
  // Q-hoist: per-wave B-fragments in registers (Q already * QSCALE)
  s8v aqL[2], aqH[2];
  {
    const int row = w * 16 + lr;
#pragma unroll
    for (int kd = 0; kd < 2; ++kd) {
      aqL[kd] = *(const s8v*)&qg[(size_t)(b * Tn + q0L + row) * Cn + h * 64 +
                                 kd * 32 + lh * 8];
      aqH[kd] = *(const s8v*)&qg[(size_t)(b * Tn + q0H + row) * Cn + h * 64 +
                                 kd * 32 + lh * 8];
    }
  }
  const int qgH = q0H + w * 16 + lr;
  const int qgL = q0L + w * 16 + lr;
  float mL = -1e30f, lL = 0.f, mH = -1e30f, lH = 0.f;
  f4v oL[4] = {}, oH[4] = {};
  stage_kv(kgb, vtb, Ks0, Vs0, 0, tid);
  __syncthreads();  // buf0 ready (barrier drains vmcnt)
  for (int kt = 0; kt <= tH; ++kt) {
    const bool cur = kt & 1;
    const u16* Kb = cur ? Ks1 : Ks0;
    const u16* Vb = cur ? Vs1 : Vs0;
    if (kt < tH)  // async-stage next tile into the other buffer
      stage_kv(kgb, vtb, cur ? Ks0 : Ks1, cur ? Vs0 : Vs1, (kt + 1) * KVB,
               tid);
    attn_step(aqH, Kb, Vb, kb0, kb1, vch, ln, lh, kt == tH, kt * KVB, qgH, mH,
              lH, oH);
    if (kt <= tL)
      attn_step(aqL, Kb, Vb, kb0, kb1, vch, ln, lh, kt == tL, kt * KVB, qgL,
                mL, lL, oL);
    __syncthreads();  // next buffer ready; this buffer's readers done
  }
  {
    float ls = lH;
    ls += __shfl_xor(ls, 16);
    ls += __shfl_xor(ls, 32);
    const float linv = 1.0f / ls;
#pragma unroll
    for (int r = 0; r < 4; ++r) {
      const float iv = __shfl(linv, (ln & 48) | (lh * 4 + r));
      const int row = q0H + w * 16 + lh * 4 + r;
#pragma unroll
      for (int n2 = 0; n2 < 4; ++n2)
        yg[(size_t)(b * Tn + row) * Cn + h * 64 + n2 * 16 + lr] =
            bfc(oH[n2][r] * iv);
    }
  }
  {
    float ls = lL;
    ls += __shfl_xor(ls, 16);
    ls += __shfl_xor(ls, 32);
    const float linv = 1.0f / ls;
#pragma unroll
    for (int r = 0; r < 4; ++r) {
      const float iv = __shfl(linv, (ln & 48) | (lh * 4 + r));
      const int row = q0L + w * 16 + lh * 4 + r;
#pragma unroll
      for (int n2 = 0; n2 < 4; ++n2)
        yg[(size_t)(b * Tn + row) * Cn + h * 64 + n2 * 16 + lr] =
            bfc(oL[n2][r] * iv);
    }
  }
}

}  // namespace

extern "C" void kernel_launch(void* const* d_in, const int* in_sizes, int n_in,
                              void* d_out, int out_size, void* d_ws,
                              size_t ws_size, hipStream_t stream) {
  (void)in_sizes; (void)n_in; (void)out_size; (void)ws_size;
  const float* x = (const float*)d_in[0];
  const float* Wk = (const float*)d_in[1];
  const float* Wq = (const float*)d_in[2];
  const float* Wv = (const float*)d_in[3];
  const float* Wp = (const float*)d_in[4];
  float* out = (float*)d_out;
  char* ws = (char*)d_ws;

  u16* xb = (u16*)(ws);              // 16.8 MB
  u16* wqt = (u16*)(ws + 16777216);  // 2 MB each
  u16* wkt = (u16*)(ws + 18874368);
  u16* wvt = (u16*)(ws + 20971520);
  u16* wpt = (u16*)(ws + 23068672);
  u16* qb = (u16*)(ws + 25165824);  // 16.8 MB each
  u16* kb = (u16*)(ws + 41943040);
  u16* vt = (u16*)(ws + 58720256);  // head-major V^T [b][h][d][t], pi-permuted
  u16* yb = (u16*)(ws + 75497472);

  cvtx<<<dim3(4096), dim3(256), 0, stream>>>(x, xb);
  wtrans<<<dim3(16, 16, 4), dim3(256), 0, stream>>>(Wq, Wk, Wv, Wp, wqt, wkt,
                                                    wvt, wpt);
  gemm_qkv<<<dim3(1536), dim3(256), 0, stream>>>(xb, wqt, wkt, wvt, qb, kb,
                                                 vt);
  attn_big<<<dim3(512), dim3(512), 0, stream>>>(qb, kb, vt, yb);
  gemm_bt<2><<<dim3(512), dim3(256), 0, stream>>>(yb, wpt, out);
}

// Round 10
// 168.975 us; speedup vs baseline: 1.1669x; 1.1040x over previous
//
#include <hip/hip_runtime.h>
#include <cstddef>
#include <cstdint>

// CausalSelfAttention, bf16-MFMA pipeline, round 10.
// B=4, T=2048, C=1024, NH=16, HS=64.
//   prep:      x fp32 -> bf16  +  W fp32 [K][N] -> W^T bf16 [N][K] (fused)
//   gemm_qkv:  fused q/k/v projection; BK=64, T2 XOR-swizzled LDS,
//              bm-sliced XCD mapping (A-slice stays hot in per-XCD L2)
//   gemm_bt<2>: output projection, same structure
//   attn_big:  unchanged from round 9 (swapped QK^T, in-lane softmax,
//              b128 PV via pi-permuted V, hoisted LDS offsets).

namespace {

typedef unsigned short u16;
typedef unsigned int u32;
typedef __attribute__((ext_vector_type(8))) short s8v;   // 8 bf16 (4 VGPR)
typedef __attribute__((ext_vector_type(4))) short s4v;   // 4 bf16 (2 VGPR)
typedef __attribute__((ext_vector_type(4))) float f4v;

constexpr int Bn = 4, Tn = 2048, Cn = 1024;
constexpr int Mn = Bn * Tn;      // 8192
constexpr int KVB = 128;         // k-tile rows
constexpr int NT128 = Tn / 128;  // 16 tiles
constexpr float QSCALE = 0.125f * 1.44269504f;  // 1/sqrt(64) * log2(e)

__device__ __forceinline__ u16 bfc(float f) {  // fp32 -> bf16 (RNE, native)
  return __builtin_bit_cast(u16, (__bf16)f);
}

__device__ __forceinline__ float ex2(float x) {
#if __has_builtin(__builtin_amdgcn_exp2f)
  return __builtin_amdgcn_exp2f(x);
#else
  return exp2f(x);
#endif
}

__device__ __forceinline__ f4v mfma16(s8v a, s8v b, f4v c) {
  return __builtin_amdgcn_mfma_f32_16x16x32_bf16(a, b, c, 0, 0, 0);
}

__device__ __forceinline__ f4v mfma16k16(s4v a, s4v b, f4v c) {
#if __has_builtin(__builtin_amdgcn_mfma_f32_16x16x16bf16_1k)
  return __builtin_amdgcn_mfma_f32_16x16x16bf16_1k(a, b, c, 0, 0, 0);
#else
  f4v d = c;
  asm("v_mfma_f32_16x16x16_bf16 %0, %1, %2, %0" : "+v"(d) : "v"(a), "v"(b));
  return d;
#endif
}

typedef __attribute__((address_space(1))) const u32 gas_u32;
typedef __attribute__((address_space(3))) u32 las_u32;
__device__ __forceinline__ void gl_lds16(const void* g, void* l) {
  __builtin_amdgcn_global_load_lds((gas_u32*)g, (las_u32*)l, 16, 0, 0);
}

// ---------------- prep: cvtx (bid<4096) + wtrans (bid>=4096) ----------------
__global__ __launch_bounds__(256) void prep(
    const float* __restrict__ x, u16* __restrict__ xb,
    const float* __restrict__ w0, const float* __restrict__ w1,
    const float* __restrict__ w2, const float* __restrict__ w3,
    u16* __restrict__ o0, u16* __restrict__ o1, u16* __restrict__ o2,
    u16* __restrict__ o3) {
  __shared__ float Tsh[64][65];
  const int bid = blockIdx.x;
  const int tid = threadIdx.x;
  if (bid < 4096) {  // x -> bf16
    const size_t i = ((size_t)bid * 256 + tid) * 8;
    const float4 a = *(const float4*)(x + i);
    const float4 b = *(const float4*)(x + i + 4);
    alignas(16) u16 t[8] = {bfc(a.x), bfc(a.y), bfc(a.z), bfc(a.w),
                            bfc(b.x), bfc(b.y), bfc(b.z), bfc(b.w)};
    *(s8v*)(xb + i) = *(const s8v*)t;
    return;
  }
  const int idx = bid - 4096;  // 0..1023
  const int wz = idx >> 8, wy = (idx >> 4) & 15, wx = idx & 15;
  const float* W;
  u16* O;
  switch (wz) {
    case 0: W = w0; O = o0; break;
    case 1: W = w1; O = o1; break;
    case 2: W = w2; O = o2; break;
    default: W = w3; O = o3; break;
  }
  const int n0 = wx * 64, k0 = wy * 64;
  {
    const int rk = tid >> 2, c0 = (tid & 3) * 16;
#pragma unroll
    for (int u = 0; u < 4; ++u) {
      const float4 v = *(const float4*)&W[(size_t)(k0 + rk) * Cn + n0 + c0 + u * 4];
      Tsh[rk][c0 + u * 4 + 0] = v.x;
      Tsh[rk][c0 + u * 4 + 1] = v.y;
      Tsh[rk][c0 + u * 4 + 2] = v.z;
      Tsh[rk][c0 + u * 4 + 3] = v.w;
    }
  }
  __syncthreads();
  {
    const int rn = tid >> 2, ck0 = (tid & 3) * 16;
    alignas(16) u16 t[16];
#pragma unroll
    for (int u = 0; u < 16; ++u) t[u] = bfc(Tsh[ck0 + u][rn]);
    *(s8v*)&O[(size_t)(n0 + rn) * Cn + k0 + ck0] = *(const s8v*)&t[0];
    *(s8v*)&O[(size_t)(n0 + rn) * Cn + k0 + ck0 + 8] = *(const s8v*)&t[8];
  }
}

// ---------------- GEMM body: BK=64, XOR-swizzled LDS ----------------
// LDS tile [128 rows][64 k] linear slots of 16B; slot s=(r,c): global chunk
// (c ^ (r&7)) stored at c -> reader XORs the same way (involution).
// OUT_MODE 0: bf16  1: V^T head-major pi-permuted  2: fp32  3: bf16 * QSCALE
template <int OUT_MODE>
__device__ __forceinline__ void gemm_body(const u16* __restrict__ A,
                                          const u16* __restrict__ Bt,
                                          void* __restrict__ Cout, int bm,
                                          int bn, u16* As, u16* Bs) {
  const int N = Cn, K = Cn;
  const int tid = threadIdx.x;
  const int l = tid & 63, w = tid >> 6;
  const int lr = l & 15, lh = l >> 4;
  const int wm = (w >> 1) * 64, wn = (w & 1) * 64;
  const u16* Ab = A + (size_t)(bm * 128) * K;
  const u16* Bb = Bt + (size_t)(bn * 128) * K;
  const int sw = lr & 7;
  f4v acc[4][4] = {};
  for (int k0 = 0; k0 < K; k0 += 64) {
    __syncthreads();  // readers done with LDS
#pragma unroll
    for (int i = 0; i < 4; ++i) {
      const int s = tid + 256 * i;
      const int r = s >> 3, c = s & 7;
      gl_lds16(Ab + (size_t)r * K + k0 + ((c ^ (r & 7)) * 8), &As[s * 8]);
    }
#pragma unroll
    for (int i = 0; i < 4; ++i) {
      const int s = tid + 256 * i;
      const int r = s >> 3, c = s & 7;
      gl_lds16(Bb + (size_t)r * K + k0 + ((c ^ (r & 7)) * 8), &Bs[s * 8]);
    }
    __syncthreads();  // stage complete (barrier drains vmcnt)
#pragma unroll
    for (int half = 0; half < 2; ++half) {
      s8v af[4], bfr[4];
#pragma unroll
      for (int i = 0; i < 4; ++i)
        af[i] = *(const s8v*)&As[(wm + i * 16 + lr) * 64 +
                                 (((half * 4 + lh) ^ sw) * 8)];
#pragma unroll
      for (int j = 0; j < 4; ++j)
        bfr[j] = *(const s8v*)&Bs[(wn + j * 16 + lr) * 64 +
                                  (((half * 4 + lh) ^ sw) * 8)];
      __builtin_amdgcn_s_setprio(1);
#pragma unroll
      for (int i = 0; i < 4; ++i)
#pragma unroll
        for (int j = 0; j < 4; ++j)
          acc[i][j] = mfma16(af[i], bfr[j], acc[i][j]);
      __builtin_amdgcn_s_setprio(0);
    }
  }
  // D layout: col = lane&15, row = (lane>>4)*4 + reg  [m89]
  if (OUT_MODE == 2) {
    float* Cf = (float*)Cout;
#pragma unroll
    for (int i = 0; i < 4; ++i) {
      const int row = bm * 128 + wm + i * 16 + lh * 4;
#pragma unroll
      for (int j = 0; j < 4; ++j) {
        const int col = bn * 128 + wn + j * 16 + lr;
#pragma unroll
        for (int r = 0; r < 4; ++r)
          Cf[(size_t)(row + r) * N + col] = acc[i][j][r];
      }
    }
  } else if (OUT_MODE == 0 || OUT_MODE == 3) {
    u16* Cb = (u16*)Cout;
    const float sc = (OUT_MODE == 3) ? QSCALE : 1.0f;
#pragma unroll
    for (int i = 0; i < 4; ++i) {
      const int row = bm * 128 + wm + i * 16 + lh * 4;
#pragma unroll
      for (int j = 0; j < 4; ++j) {
        const int col = bn * 128 + wn + j * 16 + lr;
#pragma unroll
        for (int r = 0; r < 4; ++r)
          Cb[(size_t)(row + r) * N + col] = bfc(acc[i][j][r] * sc);
      }
    }
  } else {
    // V^T head-major pi-permuted: within each 128-t tile, original
    // t = 32p+16s+4lh+j stored at p*32+lh*8+s*4+j (4-groups stay contiguous)
    u16* Vt = (u16*)Cout;
#pragma unroll
    for (int i = 0; i < 4; ++i) {
      const int row0 = bm * 128 + wm + i * 16 + lh * 4;
      const int bq = row0 >> 11;
      const int t0g = row0 & 2047;
      const int tau = t0g & 127;
      const int taup = ((tau >> 5) << 5) | (((tau >> 2) & 3) << 3) |
                       (((tau >> 4) & 1) << 2);
      const int t0p = (t0g & ~127) | taup;
#pragma unroll
      for (int j = 0; j < 4; ++j) {
        const int col = bn * 128 + wn + j * 16 + lr;
        const int hh = col >> 6, dd = col & 63;
        alignas(8) u16 t4[4];
#pragma unroll
        for (int r = 0; r < 4; ++r) t4[r] = bfc(acc[i][j][r]);
        *(s4v*)&Vt[((size_t)((bq * 16 + hh) * 64 + dd)) * Tn + t0p] =
            *(const s4v*)t4;
      }
    }
  }
}

// Fused q/k/v projection: 1536 blocks. bm-sliced XCD map: each XCD owns
// bm in [xcd*8, xcd*8+8) (A-slice 2MB -> stays in 4MB L2); (which,bn)
// combos iterate with bm-local fastest (B panel hot for 8 blocks).
__global__ __launch_bounds__(256) void gemm_qkv(
    const u16* __restrict__ A, const u16* __restrict__ btq,
    const u16* __restrict__ btk, const u16* __restrict__ btv,
    u16* __restrict__ qb, u16* __restrict__ kb, u16* __restrict__ vt) {
  __shared__ __align__(16) u16 As[8192], Bs[8192];  // 32 KB
  const int bid = blockIdx.x;  // 0..1535
  const int xcd = bid & 7, j = bid >> 3;
  const int bm = xcd * 8 + (j & 7);
  const int combo = j >> 3;  // 0..23
  const int which = combo >> 3, bn = combo & 7;
  if (which == 0)
    gemm_body<3>(A, btq, qb, bm, bn, As, Bs);  // Q pre-scaled
  else if (which == 1)
    gemm_body<0>(A, btk, kb, bm, bn, As, Bs);
  else
    gemm_body<1>(A, btv, vt, bm, bn, As, Bs);
}

template <int OUT_MODE>
__global__ __launch_bounds__(256) void gemm_bt(const u16* __restrict__ A,
                                               const u16* __restrict__ Bt,
                                               void* __restrict__ Cout) {
  __shared__ __align__(16) u16 As[8192], Bs[8192];  // 32 KB
  const int bid = blockIdx.x;  // 0..511
  const int xcd = bid & 7, j = bid >> 3;
  const int bm = xcd * 8 + (j & 7);
  const int bn = j >> 3;  // 0..7
  gemm_body<OUT_MODE>(A, Bt, Cout, bm, bn, As, Bs);
}

// ---------------- Flash attention (unchanged from round 9) ----------------
__device__ __forceinline__ void stage_kv(const u16* __restrict__ kgb,
                                         const u16* __restrict__ vtb,
                                         u16* __restrict__ Kb,
                                         u16* __restrict__ Vb, int k0,
                                         int tid) {
#pragma unroll
  for (int is = 0; is < 2; ++is) {
    const int slot = is * 512 + tid;
    const int row = slot >> 3, ch = slot & 7;
    gl_lds16(kgb + (size_t)(k0 + row) * Cn + ((ch ^ (row & 7)) * 8),
             &Kb[slot * 8]);
  }
#pragma unroll
  for (int is = 0; is < 2; ++is) {
    const int slot = is * 512 + tid;
    const int d = slot >> 4, ch = slot & 15;
    gl_lds16(vtb + (size_t)d * Tn + k0 + ((ch ^ (d & 7)) * 8), &Vb[slot * 8]);
  }
}

__device__ __forceinline__ void attn_step(const s8v (&aq)[2],
                                          const u16* __restrict__ Ks,
                                          const u16* __restrict__ Vs, int kb0,
                                          int kb1, const int (&vch)[4], int ln,
                                          int lh, bool diag, int k0, int qg,
                                          float& m_i, float& l_i, f4v* o) {
  f4v s[8] = {};
  __builtin_amdgcn_s_setprio(1);
#pragma unroll
  for (int n = 0; n < 8; ++n) {
    const s8v bk0 = *(const s8v*)&Ks[kb0 + n * 1024];
    const s8v bk1 = *(const s8v*)&Ks[kb1 + n * 1024];
    s[n] = mfma16(bk0, aq[0], s[n]);  // SWAPPED: S^T[k][q]
    s[n] = mfma16(bk1, aq[1], s[n]);
  }
  __builtin_amdgcn_s_setprio(0);
  float rm = -1e30f;
  if (diag) {
#pragma unroll
    for (int n = 0; n < 8; ++n)
#pragma unroll
      for (int r = 0; r < 4; ++r) {
        float x = s[n][r];
        if (k0 + n * 16 + lh * 4 + r > qg) x = -1e30f;
        s[n][r] = x;
        rm = fmaxf(rm, x);
      }
  } else {
#pragma unroll
    for (int n = 0; n < 8; ++n)
      rm = fmaxf(rm, fmaxf(fmaxf(s[n][0], s[n][1]), fmaxf(s[n][2], s[n][3])));
  }
  if (!__all(rm <= m_i + 11.5f)) {  // T13 defer-max
    float rr = fmaxf(rm, __shfl_xor(rm, 16));
    rr = fmaxf(rr, __shfl_xor(rr, 32));
    const float mnew = fmaxf(m_i, rr);
    const float al = ex2(m_i - mnew);
    m_i = mnew;
    l_i *= al;
#pragma unroll
    for (int r = 0; r < 4; ++r) {
      const float ar = __shfl(al, (ln & 48) | (lh * 4 + r));
#pragma unroll
      for (int n2 = 0; n2 < 4; ++n2) o[n2][r] *= ar;
    }
  }
  s4v pa[8];
  float rs = 0.f;
#pragma unroll
  for (int n = 0; n < 8; ++n) {
    const float p0 = ex2(s[n][0] - m_i);
    const float p1 = ex2(s[n][1] - m_i);
    const float p2 = ex2(s[n][2] - m_i);
    const float p3 = ex2(s[n][3] - m_i);
    rs += (p0 + p1) + (p2 + p3);
    pa[n] = (s4v){(short)bfc(p0), (short)bfc(p1), (short)bfc(p2),
                  (short)bfc(p3)};
  }
  l_i += rs;
  __builtin_amdgcn_s_setprio(1);
#pragma unroll
  for (int n2 = 0; n2 < 4; ++n2) {
#pragma unroll
    for (int p = 0; p < 4; ++p) {
      const s8v vv = *(const s8v*)&Vs[vch[p] + n2 * 2048];
      const s4v lo = {vv[0], vv[1], vv[2], vv[3]};
      const s4v hi = {vv[4], vv[5], vv[6], vv[7]};
      o[n2] = mfma16k16(pa[2 * p], lo, o[n2]);
      o[n2] = mfma16k16(pa[2 * p + 1], hi, o[n2]);
    }
  }
  __builtin_amdgcn_s_setprio(0);
}

__global__ __launch_bounds__(512) void attn_big(const u16* __restrict__ qg,
                                                const u16* __restrict__ kg,
                                                const u16* __restrict__ vtg,
                                                u16* __restrict__ yg) {
  __shared__ __align__(16) u16 Ks0[KVB * 64], Ks1[KVB * 64];  // 16 KB each
  __shared__ __align__(16) u16 Vs0[64 * KVB], Vs1[64 * KVB];  // 16 KB each
  const int tid = threadIdx.x;
  const int ln = tid & 63, w = tid >> 6;  // wave 0..7
  const int lr = ln & 15, lh = ln >> 4;
  const int bid = blockIdx.x;                  // 0..511
  const int wg = (bid & 7) * 64 + (bid >> 3);  // XCD chunking (512 % 8 == 0)
  const int bh = wg >> 3, xp = wg & 7;
  const int b = bh >> 4, h = bh & 15;
  const int tL = xp, tH = NT128 - 1 - xp;
  const int q0L = tL * 128, q0H = tH * 128;
  const u16* kgb = kg + (size_t)(b * Tn) * Cn + h * 64;
  const u16* vtb = vtg + (size_t)(bh * 64) * Tn;
  const int kb0 = lr * 64 + ((lh) ^ (lr & 7)) * 8;
  const int kb1 = lr * 64 + ((4 + lh) ^ (lr & 7)) * 8;
  int vch[4];
#pragma unroll
  for (int p = 0; p < 4; ++p)
    vch[p] = lr * 128 + ((p * 4 + lh) ^ (lr & 7)) * 8;
  s8v aqL[2], aqH[2];
  {
    const int row = w * 16 + lr;
#pragma unroll
    for (int kd = 0; kd < 2; ++kd) {
      aqL[kd] = *(const s8v*)&qg[(size_t)(b * Tn + q0L + row) * Cn + h * 64 +
                                 kd * 32 + lh * 8];
      aqH[kd] = *(const s8v*)&qg[(size_t)(b * Tn + q0H + row) * Cn + h * 64 +
                                 kd * 32 + lh * 8];
    }
  }
  const int qgH = q0H + w * 16 + lr;
  const int qgL = q0L + w * 16 + lr;
  float mL = -1e30f, lL = 0.f, mH = -1e30f, lH = 0.f;
  f4v oL[4] = {}, oH[4] = {};
  stage_kv(kgb, vtb, Ks0, Vs0, 0, tid);
  __syncthreads();  // buf0 ready (barrier drains vmcnt)
  for (int kt = 0; kt <= tH; ++kt) {
    const bool cur = kt & 1;
    const u16* Kb = cur ? Ks1 : Ks0;
    const u16* Vb = cur ? Vs1 : Vs0;
    if (kt < tH)
      stage_kv(kgb, vtb, cur ? Ks0 : Ks1, cur ? Vs0 : Vs1, (kt + 1) * KVB,
               tid);
    attn_step(aqH, Kb, Vb, kb0, kb1, vch, ln, lh, kt == tH, kt * KVB, qgH, mH,
              lH, oH);
    if (kt <= tL)
      attn_step(aqL, Kb, Vb, kb0, kb1, vch, ln, lh, kt == tL, kt * KVB, qgL,
                mL, lL, oL);
    __syncthreads();
  }
  {
    float ls = lH;
    ls += __shfl_xor(ls, 16);
    ls += __shfl_xor(ls, 32);
    const float linv = 1.0f / ls;
#pragma unroll
    for (int r = 0; r < 4; ++r) {
      const float iv = __shfl(linv, (ln & 48) | (lh * 4 + r));
      const int row = q0H + w * 16 + lh * 4 + r;
#pragma unroll
      for (int n2 = 0; n2 < 4; ++n2)
        yg[(size_t)(b * Tn + row) * Cn + h * 64 + n2 * 16 + lr] =
            bfc(oH[n2][r] * iv);
    }
  }
  {
    float ls = lL;
    ls += __shfl_xor(ls, 16);
    ls += __shfl_xor(ls, 32);
    const float linv = 1.0f / ls;
#pragma unroll
    for (int r = 0; r < 4; ++r) {
      const float iv = __shfl(linv, (ln & 48) | (lh * 4 + r));
      const int row = q0L + w * 16 + lh * 4 + r;
#pragma unroll
      for (int n2 = 0; n2 < 4; ++n2)
        yg[(size_t)(b * Tn + row) * Cn + h * 64 + n2 * 16 + lr] =
            bfc(oL[n2][r] * iv);
    }
  }
}

}  // namespace

extern "C" void kernel_launch(void* const* d_in, const int* in_sizes, int n_in,
                              void* d_out, int out_size, void* d_ws,
                              size_t ws_size, hipStream_t stream) {
  (void)in_sizes; (void)n_in; (void)out_size; (void)ws_size;
  const float* x = (const float*)d_in[0];
  const float* Wk = (const float*)d_in[1];
  const float* Wq = (const float*)d_in[2];
  const float* Wv = (const float*)d_in[3];
  const float* Wp = (const float*)d_in[4];
  float* out = (float*)d_out;
  char* ws = (char*)d_ws;

  u16* xb = (u16*)(ws);              // 16.8 MB
  u16* wqt = (u16*)(ws + 16777216);  // 2 MB each
  u16* wkt = (u16*)(ws + 18874368);
  u16* wvt = (u16*)(ws + 20971520);
  u16* wpt = (u16*)(ws + 23068672);
  u16* qb = (u16*)(ws + 25165824);  // 16.8 MB each
  u16* kb = (u16*)(ws + 41943040);
  u16* vt = (u16*)(ws + 58720256);  // head-major V^T [b][h][d][t], pi-permuted
  u16* yb = (u16*)(ws + 75497472);

  prep<<<dim3(5120), dim3(256), 0, stream>>>(x, xb, Wq, Wk, Wv, Wp, wqt, wkt,
                                             wvt, wpt);
  gemm_qkv<<<dim3(1536), dim3(256), 0, stream>>>(xb, wqt, wkt, wvt, qb, kb,
                                                 vt);
  attn_big<<<dim3(512), dim3(512), 0, stream>>>(qb, kb, vt, yb);
  gemm_bt<2><<<dim3(512), dim3(256), 0, stream>>>(yb, wpt, out);
}